// Round 1
// baseline (2022.893 us; speedup 1.0000x reference)
//
#include <hip/hip_runtime.h>

// ---------------------------------------------------------------------------
// MultiEdgeClassifier: 6-layer GCN + BN + weighted residual + edge-pair FC
// N=100k nodes, HID=128, E=1.6M edges (+N self loops), E_OUT=400k
// ---------------------------------------------------------------------------

#define HID 128

// ---------------- preprocessing: degree / norm / CSR build ----------------

__global__ void count_deg_kernel(const int* __restrict__ dst, int* __restrict__ cnt, int e) {
  int j = blockIdx.x * blockDim.x + threadIdx.x;
  if (j < e) atomicAdd(&cnt[dst[j]], 1);
}

__global__ void compute_dis_kernel(const int* __restrict__ cnt, float* __restrict__ dis, int n) {
  int i = blockIdx.x * blockDim.x + threadIdx.x;
  if (i < n) dis[i] = rsqrtf((float)(cnt[i] + 1));  // +1 self loop; deg >= 1 always
}

// exclusive scan of (cnt[i]+1) -> rs[i]; 1024 elems per block
__global__ void scan_block_kernel(const int* __restrict__ cnt, int* __restrict__ rs,
                                  int* __restrict__ partials, int n) {
  __shared__ int lds[256];
  int t = threadIdx.x;
  int base = blockIdx.x * 1024 + t * 4;
  int v[4]; int si = 0;
#pragma unroll
  for (int i = 0; i < 4; ++i) {
    int j = base + i;
    int x = (j < n) ? (cnt[j] + 1) : 0;
    v[i] = x; si += x;
  }
  int val = si;
  lds[t] = val; __syncthreads();
  for (int off = 1; off < 256; off <<= 1) {
    int x = (t >= off) ? lds[t - off] : 0;
    __syncthreads();
    val += x;
    lds[t] = val;
    __syncthreads();
  }
  if (t == 255) partials[blockIdx.x] = val;
  int run = val - si;  // exclusive prefix within block
#pragma unroll
  for (int i = 0; i < 4; ++i) {
    int j = base + i;
    if (j < n) rs[j] = run;
    run += v[i];
  }
}

__global__ void scan_partials_kernel(int* __restrict__ partials, int nb) {
  __shared__ int lds[256];
  int t = threadIdx.x;
  int v = (t < nb) ? partials[t] : 0;
  int val = v;
  lds[t] = val; __syncthreads();
  for (int off = 1; off < 256; off <<= 1) {
    int x = (t >= off) ? lds[t - off] : 0;
    __syncthreads();
    val += x;
    lds[t] = val;
    __syncthreads();
  }
  if (t < nb) partials[t] = val - v;  // exclusive
}

__global__ void scan_add_kernel(int* __restrict__ rs, const int* __restrict__ partials,
                                int n, int total) {
  int j = blockIdx.x * blockDim.x + threadIdx.x;
  if (j < n) rs[j] += partials[j >> 10];
  if (j == 0) rs[n] = total;
}

// counting-sort edges by dst; self-loops appended as j in [e, e+n)
__global__ void scatter_edges_kernel(const int* __restrict__ src, const int* __restrict__ dst,
                                     const float* __restrict__ dis, int* __restrict__ fill,
                                     int* __restrict__ s_out, float* __restrict__ n_out,
                                     int e, int n) {
  int j = blockIdx.x * blockDim.x + threadIdx.x;
  if (j >= e + n) return;
  int s, d;
  if (j < e) { s = src[j]; d = dst[j]; } else { s = j - e; d = j - e; }
  float nm = dis[s] * dis[d];
  int pos = atomicAdd(&fill[d], 1);
  s_out[pos] = s;
  n_out[pos] = nm;
}

__global__ void softmax_w_kernel(const float* __restrict__ lw, float* __restrict__ w, int l) {
  if (threadIdx.x == 0 && blockIdx.x == 0) {
    float m = lw[0];
    for (int i = 1; i < l; ++i) m = fmaxf(m, lw[i]);
    float s = 0.f;
    for (int i = 0; i < l; ++i) s += expf(lw[i] - m);
    for (int i = 0; i < l; ++i) w[i] = expf(lw[i] - m) / s;
  }
}

// ---------------- embed: x[N,16] @ W[16,128] + b ----------------

__global__ void embed_kernel(const float* __restrict__ x, const float* __restrict__ W,
                             const float* __restrict__ b, float* __restrict__ xe, int n) {
  int r = blockIdx.x * 2 + (threadIdx.x >> 7);
  int c = threadIdx.x & 127;
  if (r >= n) return;
  float acc = b[c];
#pragma unroll
  for (int k = 0; k < 16; ++k)
    acc = fmaf(x[(size_t)r * 16 + k], W[k * 128 + c], acc);
  xe[(size_t)r * 128 + c] = acc;
}

// ---------------- fp32 GEMM: C[n,128] = A[n,128] @ W[128,128] ----------------
// 64-row tile per block; A panel staged in LDS [64][132]; W staged 16 rows at a time.

__global__ __launch_bounds__(256) void gemm_x128_kernel(const float* __restrict__ A,
                                                        const float* __restrict__ W,
                                                        float* __restrict__ C, int n) {
  __shared__ float As[64][132];   // +4 pad keeps float4-align & spreads banks
  __shared__ float Ws[16][128];
  int tid = threadIdx.x;
  int row0 = blockIdx.x * 64;

  // stage A panel (64x128), float4 per thread x8
#pragma unroll
  for (int it = 0; it < 8; ++it) {
    int flat = it * 256 + tid;        // 0..2047
    int r = flat >> 5;                // 0..63
    int kq = flat & 31;               // float4 idx
    float4 v = make_float4(0.f, 0.f, 0.f, 0.f);
    int row = row0 + r;
    if (row < n) v = *(const float4*)(A + (size_t)row * 128 + kq * 4);
    *(float4*)&As[r][kq * 4] = v;
  }

  int tr = tid >> 4;   // 0..15 -> rows tr*4..+3
  int tc = tid & 15;   // 0..15 -> cols tc*4..+3 and 64+tc*4..+3
  float acc[4][8];
#pragma unroll
  for (int i = 0; i < 4; ++i)
#pragma unroll
    for (int j = 0; j < 8; ++j) acc[i][j] = 0.f;

  for (int k0 = 0; k0 < 128; k0 += 16) {
    __syncthreads();  // As ready / previous Ws reads done
    // stage Ws[16][128]
#pragma unroll
    for (int it = 0; it < 2; ++it) {
      int flat = it * 256 + tid;      // 0..511 float4 slots
      int kk = flat >> 5;
      int cq = flat & 31;
      *(float4*)&Ws[kk][cq * 4] = *(const float4*)(W + (size_t)(k0 + kk) * 128 + cq * 4);
    }
    __syncthreads();
#pragma unroll
    for (int kk = 0; kk < 16; ++kk) {
      float av[4];
#pragma unroll
      for (int i = 0; i < 4; ++i) av[i] = As[tr * 4 + i][k0 + kk];
      float4 b0 = *(const float4*)&Ws[kk][tc * 4];
      float4 b1 = *(const float4*)&Ws[kk][64 + tc * 4];
      float bv[8] = {b0.x, b0.y, b0.z, b0.w, b1.x, b1.y, b1.z, b1.w};
#pragma unroll
      for (int i = 0; i < 4; ++i)
#pragma unroll
        for (int j = 0; j < 8; ++j)
          acc[i][j] = fmaf(av[i], bv[j], acc[i][j]);
    }
  }

#pragma unroll
  for (int i = 0; i < 4; ++i) {
    int row = row0 + tr * 4 + i;
    if (row < n) {
      *(float4*)(C + (size_t)row * 128 + tc * 4) =
          make_float4(acc[i][0], acc[i][1], acc[i][2], acc[i][3]);
      *(float4*)(C + (size_t)row * 128 + 64 + tc * 4) =
          make_float4(acc[i][4], acc[i][5], acc[i][6], acc[i][7]);
    }
  }
}

// ---------------- CSR SpMM: agg[r] = sum_e norm[e]*h[src[e]] + bias ----------------
// one wave per dst row; lane handles 2 channels

__global__ __launch_bounds__(256) void spmm_kernel(const int* __restrict__ rs,
                                                   const int* __restrict__ srcs,
                                                   const float* __restrict__ norms,
                                                   const float* __restrict__ h,
                                                   const float* __restrict__ bias,
                                                   float* __restrict__ agg, int n) {
  int wid = threadIdx.x >> 6;
  int lane = threadIdx.x & 63;
  int row = blockIdx.x * 4 + wid;
  if (row >= n) return;
  int e0 = rs[row], e1 = rs[row + 1];
  float a0 = 0.f, a1 = 0.f;
  for (int e = e0; e < e1; ++e) {
    int s = srcs[e];
    float nm = norms[e];
    float2 hv = *(const float2*)(h + (size_t)s * 128 + lane * 2);
    a0 = fmaf(nm, hv.x, a0);
    a1 = fmaf(nm, hv.y, a1);
  }
  float2 b = *(const float2*)(bias + lane * 2);
  *(float2*)(agg + (size_t)row * 128 + lane * 2) = make_float2(a0 + b.x, a1 + b.y);
}

// ---------------- BN stats: per-channel sum & sumsq ----------------

__global__ void bn_stats_kernel(const float* __restrict__ agg, float* __restrict__ stats, int n) {
  int c = threadIdx.x & 127;
  int half = threadIdx.x >> 7;
  float s = 0.f, q = 0.f;
  for (int r = blockIdx.x * 2 + half; r < n; r += gridDim.x * 2) {
    float v = agg[(size_t)r * 128 + c];
    s += v;
    q = fmaf(v, v, q);
  }
  __shared__ float ls[256], lq[256];
  ls[threadIdx.x] = s; lq[threadIdx.x] = q;
  __syncthreads();
  if (half == 0) {
    atomicAdd(&stats[c], ls[c] + ls[128 + c]);
    atomicAdd(&stats[128 + c], lq[c] + lq[128 + c]);
  }
}

// ---------------- fused BN + ReLU + weighted residual ----------------

__global__ void bn_apply_kernel(const float* __restrict__ agg, const float* __restrict__ stats,
                                const float* __restrict__ gamma, const float* __restrict__ beta,
                                const float* __restrict__ wsm, int layer,
                                float* __restrict__ xe, int n) {
  size_t idx = ((size_t)blockIdx.x * blockDim.x + threadIdx.x) * 4;
  size_t tot = (size_t)n * 128;
  if (idx >= tot) return;
  int c = (int)(idx & 127);
  float w = wsm[layer];
  float invn = 1.f / (float)n;
  float4 a = *(const float4*)(agg + idx);
  float4 xv = *(const float4*)(xe + idx);
  float av[4] = {a.x, a.y, a.z, a.w};
  float xo[4] = {xv.x, xv.y, xv.z, xv.w};
#pragma unroll
  for (int j = 0; j < 4; ++j) {
    float mean = stats[c + j] * invn;
    float var = stats[128 + c + j] * invn - mean * mean;
    float inv = rsqrtf(var + 1e-5f);
    float v = (av[j] - mean) * inv * gamma[c + j] + beta[c + j];
    v = fmaxf(v, 0.f);
    xo[j] = xo[j] + w * v;
  }
  *(float4*)(xe + idx) = make_float4(xo[0], xo[1], xo[2], xo[3]);
}

// ---------------- final FC, split by linearity ----------------
// y[r] = [x[r]@fcW[0:128,0], x[r]@fcW[0:128,1], x[r]@fcW[128:256,0], x[r]@fcW[128:256,1]]

__global__ __launch_bounds__(256) void fc_node_kernel(const float* __restrict__ xe,
                                                      const float* __restrict__ fcW,
                                                      float* __restrict__ y, int n) {
  int wid = threadIdx.x >> 6;
  int lane = threadIdx.x & 63;
  int r = blockIdx.x * 4 + wid;
  if (r >= n) return;
  float2 xv = *(const float2*)(xe + (size_t)r * 128 + lane * 2);
  int k0 = lane * 2, k1 = lane * 2 + 1;
  float a00 = xv.x * fcW[k0 * 2 + 0] + xv.y * fcW[k1 * 2 + 0];
  float a01 = xv.x * fcW[k0 * 2 + 1] + xv.y * fcW[k1 * 2 + 1];
  float a10 = xv.x * fcW[(128 + k0) * 2 + 0] + xv.y * fcW[(128 + k1) * 2 + 0];
  float a11 = xv.x * fcW[(128 + k0) * 2 + 1] + xv.y * fcW[(128 + k1) * 2 + 1];
#pragma unroll
  for (int off = 32; off; off >>= 1) {
    a00 += __shfl_down(a00, off);
    a01 += __shfl_down(a01, off);
    a10 += __shfl_down(a10, off);
    a11 += __shfl_down(a11, off);
  }
  if (lane == 0) *(float4*)(y + (size_t)r * 4) = make_float4(a00, a01, a10, a11);
}

__global__ void edge_out_kernel(const float* __restrict__ y, const int* __restrict__ eo,
                                const float* __restrict__ fcb, float* __restrict__ out, int m) {
  int j = blockIdx.x * blockDim.x + threadIdx.x;
  if (j >= m) return;
  int a = eo[j], b = eo[m + j];
  float4 ya = *(const float4*)(y + (size_t)a * 4);
  float4 yb = *(const float4*)(y + (size_t)b * 4);
  out[(size_t)j * 2 + 0] = ya.x + yb.z + fcb[0];
  out[(size_t)j * 2 + 1] = ya.y + yb.w + fcb[1];
}

// ---------------------------------------------------------------------------

extern "C" void kernel_launch(void* const* d_in, const int* in_sizes, int n_in,
                              void* d_out, int out_size, void* d_ws, size_t ws_size,
                              hipStream_t stream) {
  const float* x     = (const float*)d_in[0];
  const int*   ei    = (const int*)d_in[1];
  const int*   eo    = (const int*)d_in[2];
  const float* embW  = (const float*)d_in[3];
  const float* embB  = (const float*)d_in[4];
  const float* convW = (const float*)d_in[5];
  const float* convB = (const float*)d_in[6];
  const float* gamma = (const float*)d_in[7];
  const float* beta  = (const float*)d_in[8];
  const float* lw    = (const float*)d_in[9];
  const float* fcW   = (const float*)d_in[10];
  const float* fcb   = (const float*)d_in[11];
  float* out = (float*)d_out;

  const int n = in_sizes[0] / 16;          // 100000
  const int e = in_sizes[1] / 2;           // 1600000
  const int m = in_sizes[2] / 2;           // 400000
  const int L = in_sizes[5] / (128 * 128); // 6

  const int* esrc = ei;
  const int* edst = ei + e;

  // workspace layout
  char* wsp = (char*)d_ws;
  size_t off = 0;
  auto take = [&](size_t bytes) -> void* {
    void* p = wsp + off;
    off = (off + bytes + 255) & ~(size_t)255;
    return p;
  };
  int*   cnt      = (int*)take((size_t)n * 4);
  int*   rowstart = (int*)take((size_t)(n + 1) * 4);
  int*   fillptr  = (int*)take((size_t)n * 4);
  float* dis      = (float*)take((size_t)n * 4);
  int*   partials = (int*)take(256 * 4);
  float* wsm      = (float*)take(64 * 4);
  float* stats    = (float*)take(256 * 4);
  int*   srcs     = (int*)take((size_t)(e + n) * 4);
  float* norms    = (float*)take((size_t)(e + n) * 4);
  float* xe       = (float*)take((size_t)n * 128 * 4);
  float* h        = (float*)take((size_t)n * 128 * 4);
  float* agg      = (float*)take((size_t)n * 128 * 4);
  float* y        = (float*)take((size_t)n * 4 * 4);
  if (off > ws_size) return;  // workspace too small: fail loudly (output stays poisoned)

  const int nb_scan = (n + 1023) / 1024;   // 98

  // --- preprocessing (same adjacency reused by all layers) ---
  hipMemsetAsync(cnt, 0, (size_t)n * 4, stream);
  count_deg_kernel<<<(e + 255) / 256, 256, 0, stream>>>(edst, cnt, e);
  compute_dis_kernel<<<(n + 255) / 256, 256, 0, stream>>>(cnt, dis, n);
  scan_block_kernel<<<nb_scan, 256, 0, stream>>>(cnt, rowstart, partials, n);
  scan_partials_kernel<<<1, 256, 0, stream>>>(partials, nb_scan);
  scan_add_kernel<<<(n + 255) / 256, 256, 0, stream>>>(rowstart, partials, n, e + n);
  hipMemcpyAsync(fillptr, rowstart, (size_t)n * 4, hipMemcpyDeviceToDevice, stream);
  scatter_edges_kernel<<<(e + n + 255) / 256, 256, 0, stream>>>(esrc, edst, dis, fillptr,
                                                                srcs, norms, e, n);
  softmax_w_kernel<<<1, 64, 0, stream>>>(lw, wsm, L);

  // --- embed ---
  embed_kernel<<<(n + 1) / 2, 256, 0, stream>>>(x, embW, embB, xe, n);

  // --- 6 GCN layers ---
  for (int i = 0; i < L; ++i) {
    gemm_x128_kernel<<<(n + 63) / 64, 256, 0, stream>>>(xe, convW + (size_t)i * 128 * 128, h, n);
    spmm_kernel<<<(n + 3) / 4, 256, 0, stream>>>(rowstart, srcs, norms, h,
                                                 convB + (size_t)i * 128, agg, n);
    hipMemsetAsync(stats, 0, 256 * 4, stream);
    bn_stats_kernel<<<512, 256, 0, stream>>>(agg, stats, n);
    bn_apply_kernel<<<(int)(((size_t)n * 128 / 4 + 255) / 256), 256, 0, stream>>>(
        agg, stats, gamma + (size_t)i * 128, beta + (size_t)i * 128, wsm, i, xe, n);
  }

  // --- final FC via linearity: per-node 4-vector then 16B gather per edge ---
  fc_node_kernel<<<(n + 3) / 4, 256, 0, stream>>>(xe, fcW, y, n);
  edge_out_kernel<<<(m + 255) / 256, 256, 0, stream>>>(y, eo, fcb, out, m);
}

// Round 2
// 1447.510 us; speedup vs baseline: 1.3975x; 1.3975x over previous
//
#include <hip/hip_runtime.h>

// ---------------------------------------------------------------------------
// MultiEdgeClassifier: 6-layer GCN + BN + weighted residual + edge-pair FC
// N=100k nodes, HID=128, E=1.6M edges (+N self loops), E_OUT=400k
// Round 1: bf16 h/agg/xe-copy, MFMA GEMM, packed edges, fused BN stats.
// ---------------------------------------------------------------------------

typedef __attribute__((ext_vector_type(8))) short short8;
typedef __attribute__((ext_vector_type(4))) float f32x4;

static __device__ __forceinline__ unsigned short f2bf(float f) {
  unsigned u = __float_as_uint(f);
  u = u + 0x7fffu + ((u >> 16) & 1u);   // RNE
  return (unsigned short)(u >> 16);
}
static __device__ __forceinline__ float bf2f_lo(unsigned v) {
  return __uint_as_float(v << 16);
}
static __device__ __forceinline__ float bf2f_hi(unsigned v) {
  return __uint_as_float(v & 0xffff0000u);
}
static __device__ __forceinline__ unsigned pack_bf2(float a, float b) {
  return (unsigned)f2bf(a) | ((unsigned)f2bf(b) << 16);
}

// ---------------- preprocessing: degree / norm / CSR build ----------------

__global__ void count_deg_kernel(const int* __restrict__ dst, int* __restrict__ cnt, int e) {
  int j = blockIdx.x * blockDim.x + threadIdx.x;
  if (j < e) atomicAdd(&cnt[dst[j]], 1);
}

__global__ void compute_dis_kernel(const int* __restrict__ cnt, float* __restrict__ dis, int n) {
  int i = blockIdx.x * blockDim.x + threadIdx.x;
  if (i < n) dis[i] = rsqrtf((float)(cnt[i] + 1));  // +1 self loop
}

__global__ void scan_block_kernel(const int* __restrict__ cnt, int* __restrict__ rs,
                                  int* __restrict__ partials, int n) {
  __shared__ int lds[256];
  int t = threadIdx.x;
  int base = blockIdx.x * 1024 + t * 4;
  int v[4]; int si = 0;
#pragma unroll
  for (int i = 0; i < 4; ++i) {
    int j = base + i;
    int x = (j < n) ? (cnt[j] + 1) : 0;
    v[i] = x; si += x;
  }
  int val = si;
  lds[t] = val; __syncthreads();
  for (int off = 1; off < 256; off <<= 1) {
    int x = (t >= off) ? lds[t - off] : 0;
    __syncthreads();
    val += x;
    lds[t] = val;
    __syncthreads();
  }
  if (t == 255) partials[blockIdx.x] = val;
  int run = val - si;
#pragma unroll
  for (int i = 0; i < 4; ++i) {
    int j = base + i;
    if (j < n) rs[j] = run;
    run += v[i];
  }
}

__global__ void scan_partials_kernel(int* __restrict__ partials, int nb) {
  __shared__ int lds[256];
  int t = threadIdx.x;
  int v = (t < nb) ? partials[t] : 0;
  int val = v;
  lds[t] = val; __syncthreads();
  for (int off = 1; off < 256; off <<= 1) {
    int x = (t >= off) ? lds[t - off] : 0;
    __syncthreads();
    val += x;
    lds[t] = val;
    __syncthreads();
  }
  if (t < nb) partials[t] = val - v;
}

__global__ void scan_add_kernel(int* __restrict__ rs, const int* __restrict__ partials,
                                int n, int total) {
  int j = blockIdx.x * blockDim.x + threadIdx.x;
  if (j < n) rs[j] += partials[j >> 10];
  if (j == 0) rs[n] = total;
}

// counting-sort edges by dst into packed (src, norm) records
__global__ void scatter_edges_kernel(const int* __restrict__ src, const int* __restrict__ dst,
                                     const float* __restrict__ dis, int* __restrict__ fill,
                                     int2* __restrict__ esn, int e, int n) {
  int j = blockIdx.x * blockDim.x + threadIdx.x;
  if (j >= e + n) return;
  int s, d;
  if (j < e) { s = src[j]; d = dst[j]; } else { s = j - e; d = j - e; }
  float nm = dis[s] * dis[d];
  int pos = atomicAdd(&fill[d], 1);
  esn[pos] = make_int2(s, __float_as_int(nm));
}

__global__ void softmax_w_kernel(const float* __restrict__ lw, float* __restrict__ w, int l) {
  if (threadIdx.x == 0 && blockIdx.x == 0) {
    float m = lw[0];
    for (int i = 1; i < l; ++i) m = fmaxf(m, lw[i]);
    float s = 0.f;
    for (int i = 0; i < l; ++i) s += expf(lw[i] - m);
    for (int i = 0; i < l; ++i) w[i] = expf(lw[i] - m) / s;
  }
}

// transpose conv_W to Wt[l][n][k] bf16
__global__ void transpose_w_kernel(const float* __restrict__ W, unsigned short* __restrict__ Wt,
                                   int total) {
  int t = blockIdx.x * blockDim.x + threadIdx.x;
  if (t >= total) return;
  int l = t >> 14;
  int nc = (t >> 7) & 127;
  int kk = t & 127;
  Wt[t] = f2bf(W[(size_t)l * 16384 + kk * 128 + nc]);
}

// ---------------- embed: x[N,16] @ W[16,128] + b -> xe fp32 + bf16 ----------------

__global__ void embed_kernel(const float* __restrict__ x, const float* __restrict__ W,
                             const float* __restrict__ b, float* __restrict__ xe,
                             unsigned short* __restrict__ xebf, int n) {
  int r = blockIdx.x * 2 + (threadIdx.x >> 7);
  int c = threadIdx.x & 127;
  if (r >= n) return;
  float acc = b[c];
#pragma unroll
  for (int k = 0; k < 16; ++k)
    acc = fmaf(x[(size_t)r * 16 + k], W[k * 128 + c], acc);
  xe[(size_t)r * 128 + c] = acc;
  xebf[(size_t)r * 128 + c] = f2bf(acc);
}

// ---------------- bf16 MFMA GEMM: H[n,128] = A[n,128] @ W, all bf16 ----------------
// 2x2 wave split per block: 32 rows/tile, W fragments register-resident,
// persistent grid so W is loaded once per block. No LDS, no barriers.

__global__ __launch_bounds__(256) void gemm_mfma_kernel(const unsigned short* __restrict__ Abf,
                                                        const unsigned short* __restrict__ Wt,
                                                        unsigned short* __restrict__ Hbf,
                                                        int n) {
  int tid = threadIdx.x;
  int wid = tid >> 6, lane = tid & 63;
  int wr = wid >> 1, wc = wid & 1;
  int lrow = lane & 15, lk = lane >> 4;   // lk = k-group (8 elems each)

  // preload W fragments: wfrag[n0][ks] covers cols wc*64+n0*16..+15, k ks*32..+31
  short8 wfrag[4][4];
  const short* WtS = (const short*)Wt;
#pragma unroll
  for (int n0 = 0; n0 < 4; ++n0) {
    int col = wc * 64 + n0 * 16 + lrow;
#pragma unroll
    for (int ks = 0; ks < 4; ++ks)
      wfrag[n0][ks] = *(const short8*)(WtS + (size_t)col * 128 + ks * 32 + lk * 8);
  }

  const short* AS = (const short*)Abf;
  int ntiles = (n + 31) >> 5;
  for (int tile = blockIdx.x; tile < ntiles; tile += gridDim.x) {
    int row = tile * 32 + wr * 16 + lrow;
    short8 afrag[4];
    if (row < n) {
#pragma unroll
      for (int ks = 0; ks < 4; ++ks)
        afrag[ks] = *(const short8*)(AS + (size_t)row * 128 + ks * 32 + lk * 8);
    } else {
#pragma unroll
      for (int ks = 0; ks < 4; ++ks) afrag[ks] = (short8)0;
    }
    f32x4 acc[4];
#pragma unroll
    for (int n0 = 0; n0 < 4; ++n0) acc[n0] = (f32x4)0.f;
#pragma unroll
    for (int ks = 0; ks < 4; ++ks)
#pragma unroll
      for (int n0 = 0; n0 < 4; ++n0)
        acc[n0] = __builtin_amdgcn_mfma_f32_16x16x32_bf16(afrag[ks], wfrag[n0][ks], acc[n0],
                                                          0, 0, 0);
    // C/D layout: col = lane&15, row(within 16) = lk*4 + reg
    int orow0 = tile * 32 + wr * 16 + lk * 4;
#pragma unroll
    for (int n0 = 0; n0 < 4; ++n0) {
      int col = wc * 64 + n0 * 16 + lrow;
#pragma unroll
      for (int r = 0; r < 4; ++r) {
        int orow = orow0 + r;
        if (orow < n) Hbf[(size_t)orow * 128 + col] = f2bf(acc[n0][r]);
      }
    }
  }
}

// ---------------- CSR SpMM (bf16 gather) + fused BN stats ----------------
// persistent grid; one wave per dst row; lane handles 2 channels; 4x unrolled.

__global__ __launch_bounds__(256) void spmm_kernel(const int* __restrict__ rs,
                                                   const int2* __restrict__ esn,
                                                   const unsigned* __restrict__ hb,
                                                   const float* __restrict__ bias,
                                                   unsigned* __restrict__ aggbf,
                                                   float* __restrict__ stats, int n) {
  int tid = threadIdx.x;
  int wid = tid >> 6, lane = tid & 63;
  float b0 = bias[2 * lane], b1 = bias[2 * lane + 1];
  float s0 = 0.f, s1 = 0.f, q0 = 0.f, q1 = 0.f;
  for (int row = blockIdx.x * 4 + wid; row < n; row += gridDim.x * 4) {
    int e0 = rs[row], e1 = rs[row + 1];
    float a0 = 0.f, a1 = 0.f;
    int e = e0;
    for (; e + 4 <= e1; e += 4) {
      int2 p0 = esn[e], p1 = esn[e + 1], p2 = esn[e + 2], p3 = esn[e + 3];
      unsigned v0 = hb[(size_t)p0.x * 64 + lane];
      unsigned v1 = hb[(size_t)p1.x * 64 + lane];
      unsigned v2 = hb[(size_t)p2.x * 64 + lane];
      unsigned v3 = hb[(size_t)p3.x * 64 + lane];
      float n0 = __int_as_float(p0.y), n1 = __int_as_float(p1.y);
      float n2 = __int_as_float(p2.y), n3 = __int_as_float(p3.y);
      a0 = fmaf(n0, bf2f_lo(v0), a0); a1 = fmaf(n0, bf2f_hi(v0), a1);
      a0 = fmaf(n1, bf2f_lo(v1), a0); a1 = fmaf(n1, bf2f_hi(v1), a1);
      a0 = fmaf(n2, bf2f_lo(v2), a0); a1 = fmaf(n2, bf2f_hi(v2), a1);
      a0 = fmaf(n3, bf2f_lo(v3), a0); a1 = fmaf(n3, bf2f_hi(v3), a1);
    }
    for (; e < e1; ++e) {
      int2 p = esn[e];
      unsigned v = hb[(size_t)p.x * 64 + lane];
      float nm = __int_as_float(p.y);
      a0 = fmaf(nm, bf2f_lo(v), a0);
      a1 = fmaf(nm, bf2f_hi(v), a1);
    }
    a0 += b0; a1 += b1;
    aggbf[(size_t)row * 64 + lane] = pack_bf2(a0, a1);
    s0 += a0; s1 += a1;
    q0 = fmaf(a0, a0, q0); q1 = fmaf(a1, a1, q1);
  }
  __shared__ float red[4][256];
  red[0][tid] = s0; red[1][tid] = s1; red[2][tid] = q0; red[3][tid] = q1;
  __syncthreads();
  float v = red[wid][lane] + red[wid][64 + lane] + red[wid][128 + lane] + red[wid][192 + lane];
  int c = (wid == 0) ? (2 * lane) : (wid == 1) ? (2 * lane + 1)
        : (wid == 2) ? (128 + 2 * lane) : (129 + 2 * lane);
  atomicAdd(&stats[c], v);
}

// ---------------- fused BN + ReLU + weighted residual ----------------
// lane handles 2 channels; updates fp32 xe and bf16 copy.

__global__ void bn_apply_kernel(const unsigned* __restrict__ aggbf,
                                const float* __restrict__ stats,
                                const float* __restrict__ gamma, const float* __restrict__ beta,
                                const float* __restrict__ wsm, int layer,
                                float* __restrict__ xe, unsigned* __restrict__ xebf2, int n) {
  int idx = blockIdx.x * blockDim.x + threadIdx.x;   // n*64 threads
  if (idx >= n * 64) return;
  int lpos = idx & 63;
  int c0 = 2 * lpos, c1 = c0 + 1;
  float w = wsm[layer];
  float invn = 1.f / (float)n;
  float m0 = stats[c0] * invn, m1 = stats[c1] * invn;
  float var0 = stats[128 + c0] * invn - m0 * m0;
  float var1 = stats[128 + c1] * invn - m1 * m1;
  float sc0 = gamma[c0] * rsqrtf(var0 + 1e-5f);
  float sc1 = gamma[c1] * rsqrtf(var1 + 1e-5f);
  float sh0 = beta[c0] - m0 * sc0;
  float sh1 = beta[c1] - m1 * sc1;
  unsigned av = aggbf[idx];
  float2 xv = *(const float2*)(xe + (size_t)idx * 2);
  float v0 = fmaxf(fmaf(bf2f_lo(av), sc0, sh0), 0.f);
  float v1 = fmaxf(fmaf(bf2f_hi(av), sc1, sh1), 0.f);
  float xn0 = fmaf(w, v0, xv.x);
  float xn1 = fmaf(w, v1, xv.y);
  *(float2*)(xe + (size_t)idx * 2) = make_float2(xn0, xn1);
  xebf2[idx] = pack_bf2(xn0, xn1);
}

// ---------------- final FC via linearity ----------------

__global__ __launch_bounds__(256) void fc_node_kernel(const float* __restrict__ xe,
                                                      const float* __restrict__ fcW,
                                                      float* __restrict__ y, int n) {
  int wid = threadIdx.x >> 6;
  int lane = threadIdx.x & 63;
  int r = blockIdx.x * 4 + wid;
  if (r >= n) return;
  float2 xv = *(const float2*)(xe + (size_t)r * 128 + lane * 2);
  int k0 = lane * 2, k1 = lane * 2 + 1;
  float a00 = xv.x * fcW[k0 * 2 + 0] + xv.y * fcW[k1 * 2 + 0];
  float a01 = xv.x * fcW[k0 * 2 + 1] + xv.y * fcW[k1 * 2 + 1];
  float a10 = xv.x * fcW[(128 + k0) * 2 + 0] + xv.y * fcW[(128 + k1) * 2 + 0];
  float a11 = xv.x * fcW[(128 + k0) * 2 + 1] + xv.y * fcW[(128 + k1) * 2 + 1];
#pragma unroll
  for (int off = 32; off; off >>= 1) {
    a00 += __shfl_down(a00, off);
    a01 += __shfl_down(a01, off);
    a10 += __shfl_down(a10, off);
    a11 += __shfl_down(a11, off);
  }
  if (lane == 0) *(float4*)(y + (size_t)r * 4) = make_float4(a00, a01, a10, a11);
}

__global__ void edge_out_kernel(const float* __restrict__ y, const int* __restrict__ eo,
                                const float* __restrict__ fcb, float* __restrict__ out, int m) {
  int j = blockIdx.x * blockDim.x + threadIdx.x;
  if (j >= m) return;
  int a = eo[j], b = eo[m + j];
  float4 ya = *(const float4*)(y + (size_t)a * 4);
  float4 yb = *(const float4*)(y + (size_t)b * 4);
  out[(size_t)j * 2 + 0] = ya.x + yb.z + fcb[0];
  out[(size_t)j * 2 + 1] = ya.y + yb.w + fcb[1];
}

// ---------------------------------------------------------------------------

extern "C" void kernel_launch(void* const* d_in, const int* in_sizes, int n_in,
                              void* d_out, int out_size, void* d_ws, size_t ws_size,
                              hipStream_t stream) {
  const float* x     = (const float*)d_in[0];
  const int*   ei    = (const int*)d_in[1];
  const int*   eo    = (const int*)d_in[2];
  const float* embW  = (const float*)d_in[3];
  const float* embB  = (const float*)d_in[4];
  const float* convW = (const float*)d_in[5];
  const float* convB = (const float*)d_in[6];
  const float* gamma = (const float*)d_in[7];
  const float* beta  = (const float*)d_in[8];
  const float* lw    = (const float*)d_in[9];
  const float* fcW   = (const float*)d_in[10];
  const float* fcb   = (const float*)d_in[11];
  float* out = (float*)d_out;

  const int n = in_sizes[0] / 16;          // 100000
  const int e = in_sizes[1] / 2;           // 1600000
  const int m = in_sizes[2] / 2;           // 400000
  const int L = in_sizes[5] / (128 * 128); // 6

  const int* esrc = ei;
  const int* edst = ei + e;

  char* wsp = (char*)d_ws;
  size_t off = 0;
  auto take = [&](size_t bytes) -> void* {
    void* p = wsp + off;
    off = (off + bytes + 255) & ~(size_t)255;
    return p;
  };
  int*            cnt      = (int*)take((size_t)n * 4);
  int*            rowstart = (int*)take((size_t)(n + 1) * 4);
  int*            fillptr  = (int*)take((size_t)n * 4);
  float*          dis      = (float*)take((size_t)n * 4);
  int*            partials = (int*)take(256 * 4);
  float*          wsm      = (float*)take(64 * 4);
  float*          stats    = (float*)take((size_t)L * 256 * 4);
  int2*           esn      = (int2*)take((size_t)(e + n) * 8);
  float*          xe       = (float*)take((size_t)n * 128 * 4);
  unsigned short* xebf     = (unsigned short*)take((size_t)n * 128 * 2);
  unsigned short* hbf      = (unsigned short*)take((size_t)n * 128 * 2);
  unsigned*       aggbf    = (unsigned*)take((size_t)n * 64 * 4);
  unsigned short* Wt       = (unsigned short*)take((size_t)L * 128 * 128 * 2);
  float*          y        = (float*)take((size_t)n * 4 * 4);
  if (off > ws_size) return;

  const int nb_scan = (n + 1023) / 1024;

  // --- preprocessing ---
  hipMemsetAsync(cnt, 0, (size_t)n * 4, stream);
  hipMemsetAsync(stats, 0, (size_t)L * 256 * 4, stream);
  count_deg_kernel<<<(e + 255) / 256, 256, 0, stream>>>(edst, cnt, e);
  compute_dis_kernel<<<(n + 255) / 256, 256, 0, stream>>>(cnt, dis, n);
  scan_block_kernel<<<nb_scan, 256, 0, stream>>>(cnt, rowstart, partials, n);
  scan_partials_kernel<<<1, 256, 0, stream>>>(partials, nb_scan);
  scan_add_kernel<<<(n + 255) / 256, 256, 0, stream>>>(rowstart, partials, n, e + n);
  hipMemcpyAsync(fillptr, rowstart, (size_t)n * 4, hipMemcpyDeviceToDevice, stream);
  scatter_edges_kernel<<<(e + n + 255) / 256, 256, 0, stream>>>(esrc, edst, dis, fillptr,
                                                                esn, e, n);
  softmax_w_kernel<<<1, 64, 0, stream>>>(lw, wsm, L);
  transpose_w_kernel<<<(L * 16384 + 255) / 256, 256, 0, stream>>>(convW, Wt, L * 16384);

  // --- embed ---
  embed_kernel<<<(n + 1) / 2, 256, 0, stream>>>(x, embW, embB, xe, xebf, n);

  // --- 6 GCN layers ---
  for (int i = 0; i < L; ++i) {
    gemm_mfma_kernel<<<1024, 256, 0, stream>>>(xebf, Wt + (size_t)i * 16384, hbf, n);
    spmm_kernel<<<2048, 256, 0, stream>>>(rowstart, esn, (const unsigned*)hbf,
                                          convB + (size_t)i * 128, aggbf,
                                          stats + (size_t)i * 256, n);
    bn_apply_kernel<<<(n * 64 + 255) / 256, 256, 0, stream>>>(
        aggbf, stats + (size_t)i * 256, gamma + (size_t)i * 128, beta + (size_t)i * 128,
        wsm, i, xe, (unsigned*)xebf, n);
  }

  // --- final FC via linearity ---
  fc_node_kernel<<<(n + 3) / 4, 256, 0, stream>>>(xe, fcW, y, n);
  edge_out_kernel<<<(m + 255) / 256, 256, 0, stream>>>(y, eo, fcb, out, m);
}